// Round 7
// baseline (419.903 us; speedup 1.0000x reference)
//
#include <hip/hip_runtime.h>
#include <hip/hip_cooperative_groups.h>
#include <math.h>

namespace cg = cooperative_groups;

// NormalLoss: for each template vertex (M=6890), take the K=15 scan points
// (N=20000) with LARGEST distance, among them pick the min-angle normal
// match, loss = mean ||sv[sel]-tv||.
//
// Round-12: FULL REVERT of the octant excursion (rounds 8-11 ledger: all
// octant-knn variants 48-54 us vs radial baseline 30.5; R5's bitonic merge
// +6 us proved insert machinery was never dominant; cross-round constancy
// under 3 different sort pipelines pins octant-knn itself as the hot spot).
// Back to the PROVEN radial phases (R1, absmax 0.0, 30.5 us), re-orchestrated
// as ONE cooperative kernel:
//   phase1 hist -> grid.sync -> phase2 scan_scatter -> grid.sync ->
//   phase3 knn (radial suffix bound, serial sorted insert) -> grid.sync ->
//   block0 reduce.
// Rationale: per-phase work models sum to ~12-16 us; the rest of the 30.5
// was multi-dispatch launch/drain glue (rocprof.md: ~10 us launch overhead
// dominates small kernels). One dispatch removes 3 kernel boundaries + the
// memset. Grid sized via occupancy API (co-residency guaranteed), grid-
// stride in all phases; on cooperative-launch failure falls back to the
// exact R1 4-kernel pipeline.
// Banned (ledger): same-address atomic tails (1723 RMW = 25-35 us);
// per-thread O(N)/O(nblk) un-unrolled serial global-load loops (~450cy/load).

constexpr int K = 15;
constexpr int NBUCK = 256;
constexpr int WAVES = 4;     // waves (=vertices) per knn unit

__device__ __forceinline__ int bucket_of(float k2) {
    int b = (int)(k2 * 8.0f);           // 0.125-wide buckets over |p|^2 in [0,32)
    b = b > (NBUCK - 1) ? (NBUCK - 1) : b;
    return (NBUCK - 1) - b;             // bucket 0 = largest |p|
}

// ---------------- phase bodies (verbatim R1 logic, LDS passed in) --------

__device__ __forceinline__ void phase_hist(
    int c, const float* __restrict__ sv, int* __restrict__ blkhist, int N,
    int* h)
{
    const int t = threadIdx.x;
    h[t] = 0;
    __syncthreads();
    int i = c * 256 + t;
    if (i < N) {
        float x = sv[3*i], y = sv[3*i+1], z = sv[3*i+2];
        atomicAdd(&h[bucket_of(fmaf(x, x, fmaf(y, y, z*z)))], 1);
    }
    __syncthreads();
    blkhist[c * NBUCK + t] = h[t];   // full-row overwrite (poison-safe)
    __syncthreads();                 // LDS safe for next grid-stride iter
}

__device__ __forceinline__ void phase_scan_scatter(
    int blk, const float* __restrict__ sv, const int* __restrict__ blkhist,
    float4* __restrict__ sorted, float* __restrict__ smax,
    int N, int nb, int nblk,
    int* tmp, int* startSh, int* cursor)
{
    const int t = threadIdx.x;

    // column sums over block rows (coalesced; unrolled so loads pipeline —
    // R1-proven; do NOT drop the unroll, ledger r8/r9)
    int mine = 0, total = 0;
#pragma unroll 8
    for (int b = 0; b < nblk; ++b) {
        int v = blkhist[b * NBUCK + t];
        if (b < blk) mine += v;
        total += v;
    }
    tmp[t] = total;
    __syncthreads();
    // Kogge-Stone inclusive scan over buckets
    for (int d = 1; d < NBUCK; d <<= 1) {
        int u = (t >= d) ? tmp[t - d] : 0;
        __syncthreads();
        tmp[t] += u;
        __syncthreads();
    }
    int startv = tmp[t] - total;        // exclusive bucket start
    startSh[t] = startv;
    cursor[t]  = startv + mine;         // this block's write base per bucket
    __syncthreads();

    if (blk == 0) {
        // smax[j]: |p| upper bound for sorted positions >= j*64 (exact,
        // independent of within-bucket order)
        for (int j = t; j < nb; j += 256) {
            int pos = j * 64;
            int lo = 0, hi = NBUCK - 1;
            while (lo < hi) {
                int mid = (lo + hi + 1) >> 1;
                if (startSh[mid] <= pos) lo = mid; else hi = mid - 1;
            }
            int bOrig = (NBUCK - 1) - lo;
            smax[j] = sqrtf((float)(bOrig + 1) * 0.125f);
        }
    }

    int i = blk * 256 + t;
    if (i < N) {
        float x = sv[3*i], y = sv[3*i+1], z = sv[3*i+2];
        float k2 = fmaf(x, x, fmaf(y, y, z*z));
        int pos = atomicAdd(&cursor[bucket_of(k2)], 1);   // LDS atomic
        sorted[pos] = make_float4(x, y, z, __int_as_float(i));
    }
    __syncthreads();                 // LDS safe for next grid-stride iter
}

template<bool SORTED>
__device__ __forceinline__ void phase_knn(
    int u,
    const float4* __restrict__ pts, const float* __restrict__ smax,
    const float* __restrict__ sv, const float* __restrict__ tv,
    const float* __restrict__ sn, const float* __restrict__ tn,
    float* __restrict__ partial, int N, int M, float invM,
    float* bsum)
{
    const int lane = threadIdx.x & 63;
    const int w    = threadIdx.x >> 6;
    const int m    = u * WAVES + w;
    const bool valid = (m < M);

    float contrib = 0.0f;
    if (valid) {
        const float tvx = tv[3*m], tvy = tv[3*m+1], tvz = tv[3*m+2];
        const float tlen = sqrtf(tvx*tvx + tvy*tvy + tvz*tvz);

        // ---- bootstrap: bitonic-sort first 64 points desc by (d2, -idx) ----
        float v; int idx;
        {
            int l = (lane < N) ? lane : 0;
            float px, py, pz;
            if (SORTED) {
                float4 q = pts[l];
                px = q.x; py = q.y; pz = q.z; idx = __float_as_int(q.w);
            } else {
                px = sv[3*l]; py = sv[3*l+1]; pz = sv[3*l+2]; idx = l;
            }
            float dx = px - tvx, dy = py - tvy, dz = pz - tvz;
            v = fmaf(dx, dx, fmaf(dy, dy, dz * dz));
            if (lane >= N) { v = -1.0f; idx = 0x7FFFFFFF; }
        }
#pragma unroll
        for (int k = 2; k <= 64; k <<= 1) {
#pragma unroll
            for (int j = k >> 1; j > 0; j >>= 1) {
                float ov = __shfl_xor(v, j);
                int   oi = __shfl_xor(idx, j);
                bool up    = ((lane & k) == 0);   // descending segment
                bool lower = ((lane & j) == 0);
                bool mine  = (v > ov) || (v == ov && idx < oi); // total order
                bool keep  = lower ? (up ? mine : !mine) : (up ? !mine : mine);
                if (!keep) { v = ov; idx = oi; }
            }
        }
        // lanes 0..K-1 now hold the exact top-K of the first 64 (sorted desc)
        float eV = (lane < K) ? v : -1.0f;
        int   eI = idx;
        float thr = __shfl(v, K - 1);   // current 15th-largest d2

        // ---- main scan ----
        for (int ib = 64; ib < N; ib += 64) {
            int  i   = ib + lane;
            bool has = (i < N);
            // point loads issue FIRST so they overlap the smax scalar load
            float d2; int oi2;
            if (SORTED) {
                float4 q = pts[has ? i : 0];
                float bnd = smax[ib >> 6] + tlen;      // upper bound on remaining d
                if (bnd * bnd * 1.00001f < thr) break; // margin covers fp rounding
                float dx = q.x - tvx, dy = q.y - tvy, dz = q.z - tvz;
                d2 = fmaf(dx, dx, fmaf(dy, dy, dz * dz));
                oi2 = __float_as_int(q.w);
            } else {
                int g = has ? i : 0;
                float dx = sv[3*g] - tvx, dy = sv[3*g+1] - tvy, dz = sv[3*g+2] - tvz;
                d2 = fmaf(dx, dx, fmaf(dy, dy, dz * dz));
                oi2 = i;
            }
            // >= : an equal-d2 candidate with lower original idx must displace
            unsigned long long mb = __ballot(has && (d2 >= thr));
            while (mb) {
                int src = __ffsll(mb) - 1;
                mb &= mb - 1;
                float cv = __shfl(d2, src);
                int   ci = __shfl(oi2, src);
                unsigned long long bb =
                    __ballot((eV > cv) || (eV == cv && eI < ci)) & 0x7FFFull;
                int p = __popcll(bb);
                if (p < K) {   // wave-uniform
                    float uv = __shfl_up(eV, 1);
                    int   ui = __shfl_up(eI, 1);
                    if (lane < K) {
                        if (lane == p)      { eV = cv; eI = ci; }
                        else if (lane > p)  { eV = uv; eI = ui; }
                    }
                    thr = __shfl(eV, K - 1);
                    if (mb) mb &= __ballot(d2 >= thr);
                }
            }
        }

        // ---- epilogue: argmin angle, tie-break by top-k rank (= lane) ----
        const float tnx = tn[3*m], tny = tn[3*m+1], tnz = tn[3*m+2];
        float ang = 3.0e38f;
        int myI = eI;
        if (lane < K && myI != 0x7FFFFFFF) {
            float dot = sn[3*myI]*tnx + sn[3*myI+1]*tny + sn[3*myI+2]*tnz;
            dot = fminf(1.0f, fmaxf(-1.0f, dot));
            ang = acosf(dot) * 57.29577951308232f;   // degrees, matches jnp
        }
        float ba = ang; int br = lane; int bi = myI;
#pragma unroll
        for (int s = 1; s < 16; s <<= 1) {
            float oa  = __shfl_xor(ba, s);
            int   orr = __shfl_xor(br, s);
            int   oi  = __shfl_xor(bi, s);
            bool take = (oa < ba) || (oa == ba && orr < br);
            if (take) { ba = oa; br = orr; bi = oi; }
        }
        if (lane == 0) {
            float dx = sv[3*bi]   - tvx;
            float dy = sv[3*bi+1] - tvy;
            float dz = sv[3*bi+2] - tvz;
            contrib = sqrtf(dx*dx + dy*dy + dz*dz) * invM;
        }
    }

    if (lane == 0) bsum[w] = contrib;
    __syncthreads();
    if (threadIdx.x == 0)
        partial[u] = bsum[0] + bsum[1] + bsum[2] + bsum[3];
    __syncthreads();                 // bsum safe for next grid-stride iter
}

// ---------------- cooperative mega-kernel --------------------------------

__global__ __launch_bounds__(256, 4) void mega_kernel(
    const float* __restrict__ sv, const float* __restrict__ tv,
    const float* __restrict__ sn, const float* __restrict__ tn,
    float4* __restrict__ sorted, float* __restrict__ smaxp,
    int* __restrict__ blkhist, float* __restrict__ partial,
    float* __restrict__ out,
    int N, int M, int nb, int nblk, float invM, int nUnits)
{
    __shared__ int ldsA[NBUCK];
    __shared__ int ldsB[NBUCK];
    __shared__ int ldsC[NBUCK];
    __shared__ float bsum[WAVES];
    cg::grid_group grid = cg::this_grid();
    const int bid = blockIdx.x;
    const int G   = gridDim.x;

    for (int c = bid; c < nblk; c += G)
        phase_hist(c, sv, blkhist, N, ldsA);
    grid.sync();
    for (int c = bid; c < nblk; c += G)
        phase_scan_scatter(c, sv, blkhist, sorted, smaxp, N, nb, nblk,
                           ldsA, ldsB, ldsC);
    grid.sync();
    for (int u = bid; u < nUnits; u += G)
        phase_knn<true>(u, sorted, smaxp, sv, tv, sn, tn, partial,
                        N, M, invM, bsum);
    grid.sync();
    if (bid == 0) {     // final reduce (R1 reduce body)
        float s = 0.0f;
        for (int i = threadIdx.x; i < nUnits; i += 256) s += partial[i];
#pragma unroll
        for (int d = 1; d < 64; d <<= 1) s += __shfl_xor(s, d);
        const int lane = threadIdx.x & 63, w = threadIdx.x >> 6;
        if (lane == 0) bsum[w] = s;
        __syncthreads();
        if (threadIdx.x == 0) out[0] = bsum[0] + bsum[1] + bsum[2] + bsum[3];
    }
}

// ---------------- classic fallback kernels (exact R1 pipeline) -----------

__global__ __launch_bounds__(256) void hist_kernel(
    const float* __restrict__ sv, int* __restrict__ blkhist, int N)
{
    __shared__ int h[NBUCK];
    phase_hist(blockIdx.x, sv, blkhist, N, h);
}

__global__ __launch_bounds__(256) void scan_scatter_kernel(
    const float* __restrict__ sv, const int* __restrict__ blkhist,
    float4* __restrict__ sorted, float* __restrict__ smax,
    int N, int nb, int nblk)
{
    __shared__ int tmp[NBUCK];
    __shared__ int startSh[NBUCK];
    __shared__ int cursor[NBUCK];
    phase_scan_scatter(blockIdx.x, sv, blkhist, sorted, smax, N, nb, nblk,
                       tmp, startSh, cursor);
}

template<bool SORTED>
__global__ __launch_bounds__(WAVES * 64) void knn_loss_kernel(
    const float4* __restrict__ pts, const float* __restrict__ smax,
    const float* __restrict__ sv, const float* __restrict__ tv,
    const float* __restrict__ sn, const float* __restrict__ tn,
    float* __restrict__ partial, int N, int M, float invM)
{
    __shared__ float bsum[WAVES];
    phase_knn<SORTED>(blockIdx.x, pts, smax, sv, tv, sn, tn, partial,
                      N, M, invM, bsum);
}

__global__ __launch_bounds__(256) void reduce_kernel(
    const float* __restrict__ partial, float* __restrict__ out, int n)
{
    __shared__ float sh[4];
    const int lane = threadIdx.x & 63;
    const int w    = threadIdx.x >> 6;
    float s = 0.0f;
    for (int i = threadIdx.x; i < n; i += 256) s += partial[i];
#pragma unroll
    for (int d = 1; d < 64; d <<= 1) s += __shfl_xor(s, d);
    if (lane == 0) sh[w] = s;
    __syncthreads();
    if (threadIdx.x == 0) out[0] = sh[0] + sh[1] + sh[2] + sh[3];
}

// ---------------- launch ---------------------------------------------------

extern "C" void kernel_launch(void* const* d_in, const int* in_sizes, int n_in,
                              void* d_out, int out_size, void* d_ws, size_t ws_size,
                              hipStream_t stream) {
    const float* sv = (const float*)d_in[0];   // scan_vertices     [1,N,3]
    const float* tv = (const float*)d_in[1];   // template_vertices [1,M,3]
    const float* sn = (const float*)d_in[2];   // scan_normals      [N,3]
    const float* tn = (const float*)d_in[3];   // template_normals  [M,3]
    // d_in[4] = K_knn (fixed 15, compile-time)

    int N = in_sizes[0] / 3;
    int M = in_sizes[1] / 3;
    int nb = (N + 63) / 64;
    float* out = (float*)d_out;
    float invM = 1.0f / (float)M;
    int nUnits = (M + WAVES - 1) / WAVES;      // 1723
    int nblk   = (N + 255) / 256;              // 79

    // d_ws layout: [sorted N float4][smax nb][blkhist nblk*256][partial nUnits]
    size_t offSorted  = 0;
    size_t offSmax    = offSorted + (size_t)N * sizeof(float4);
    size_t offHist    = (offSmax + (size_t)nb * sizeof(float) + 15) & ~(size_t)15;
    size_t offPartial = offHist + (size_t)nblk * NBUCK * sizeof(int);
    size_t need       = offPartial + (size_t)nUnits * sizeof(float);

    if (ws_size >= need) {
        float4* sorted  = (float4*)((char*)d_ws + offSorted);
        float*  smaxp   = (float*) ((char*)d_ws + offSmax);
        int*    blkhist = (int*)   ((char*)d_ws + offHist);
        float*  partial = (float*) ((char*)d_ws + offPartial);

        // co-residency-safe grid size (computed once)
        static int gBlocks = 0;
        if (gBlocks == 0) {
            int perCU = 0;
            hipError_t oe = hipOccupancyMaxActiveBlocksPerMultiprocessor(
                &perCU, (const void*)mega_kernel, 256, 0);
            int numCU = 256;   // MI355X default
            hipDeviceProp_t prop;
            int dev = 0;
            if (hipGetDevice(&dev) == hipSuccess &&
                hipGetDeviceProperties(&prop, dev) == hipSuccess)
                numCU = prop.multiProcessorCount;
            if (oe != hipSuccess || perCU < 1) perCU = 1;
            gBlocks = perCU * numCU;
        }
        int G = gBlocks;
        if (G > nUnits) G = nUnits;
        if (G < 1) G = 1;

        void* args[] = { (void*)&sv, (void*)&tv, (void*)&sn, (void*)&tn,
                         (void*)&sorted, (void*)&smaxp, (void*)&blkhist,
                         (void*)&partial, (void*)&out,
                         (void*)&N, (void*)&M, (void*)&nb, (void*)&nblk,
                         (void*)&invM, (void*)&nUnits };
        hipError_t e = hipLaunchCooperativeKernel(
            (const void*)mega_kernel, dim3(G), dim3(256), args, 0, stream);
        if (e != hipSuccess) {
            (void)hipGetLastError();   // clear; fall back to classic R1 pipeline
            hist_kernel        <<<nblk, 256, 0, stream>>>(sv, blkhist, N);
            scan_scatter_kernel<<<nblk, 256, 0, stream>>>(sv, blkhist, sorted,
                                                          smaxp, N, nb, nblk);
            knn_loss_kernel<true><<<nUnits, WAVES * 64, 0, stream>>>(
                sorted, smaxp, sv, tv, sn, tn, partial, N, M, invM);
            reduce_kernel      <<<1, 256, 0, stream>>>(partial, out, nUnits);
        }
    } else if (ws_size >= (size_t)nUnits * sizeof(float)) {
        float* partial = (float*)d_ws;
        knn_loss_kernel<false><<<nUnits, WAVES * 64, 0, stream>>>(
            nullptr, nullptr, sv, tv, sn, tn, partial, N, M, invM);
        reduce_kernel<<<1, 256, 0, stream>>>(partial, out, nUnits);
    }
}

// Round 8
// 48.904 us; speedup vs baseline: 8.5863x; 8.5863x over previous
//
#include <hip/hip_runtime.h>
#include <math.h>

// NormalLoss: for each template vertex (M=6890), take the K=15 scan points
// (N=20000) with LARGEST distance, among them pick the min-angle normal
// match, loss = mean ||sv[sel]-tv||.
//
// Round-14: R0 (proven 30.5 us, absmax 0.0) + exact per-chunk AABB skip.
//   Ledger: cooperative launch + device queries in kernel_launch = 420 us
//   disaster (graph-capture tripwire) -- BANNED. Octant 8-sub-scan
//   restructure = 48-54 us -- BANNED. Same-address atomic tails BANNED.
//   Per-thread serial wide-row column sums (NB>256) BANNED (r9: ~38 us).
//   This round keeps R0's exact 4-dispatch structure and machinery:
//     hist(256 buckets) -> scan_scatter(unroll-8 column sums, KS scan,
//     scatter via LDS cursors) -> knn(bitonic bootstrap, linear scan,
//     radial suffix break, serial sorted insert) -> reduce.
//   Delta: sort key = (32 coarse radial shells, octant) -- still 256
//   buckets so R0's scan machinery is reused verbatim; radial suffix
//   break preserved (shell-major). Scatter also builds EXACT per-64-chunk
//   AABBs via 6 global atomicMin/Max per point (monotone-uint encoding;
//   ~120K atomics over ~1900 addresses). Box init rides in hist (separate
//   dispatch => race-free, no extra launch). knn skips chunks whose exact
//   box bound Sum_i max((lo_i-t_i)^2,(hi_i-t_i)^2) < thr (*1.00001 margin)
//   -- such chunks provably hold no top-K member => output bit-identical.
//   Meta (smax + box) is prefetched one chunk ahead: no serial latency add.

constexpr int K = 15;
constexpr int NSH = 32;            // radial shells, |p|^2 step 1.0
constexpr int NBUCK = 256;         // 32 shells x 8 octants
constexpr int WAVES = 4;           // waves (=vertices) per block in knn

__device__ __forceinline__ int bucket_of(float x, float y, float z) {
    float k2 = fmaf(x, x, fmaf(y, y, z * z));
    int b = (k2 >= (float)(NSH - 1)) ? (NSH - 1) : (int)k2;  // clamp, no UB
    int fb = (NSH - 1) - b;            // 0 = outermost shell
    int o = (x < 0.0f ? 1 : 0) | (y < 0.0f ? 2 : 0) | (z < 0.0f ? 4 : 0);
    return (fb << 3) | o;              // shell-major, octant-minor
}
// monotone float<->uint encoding (order-preserving for atomicMin/Max)
__device__ __forceinline__ unsigned encf(float f) {
    unsigned b = __float_as_uint(f);
    return (b >> 31) ? ~b : (b | 0x80000000u);
}
__device__ __forceinline__ float decf(unsigned u) {
    return (u >> 31) ? __uint_as_float(u ^ 0x80000000u)
                     : __uint_as_float(~u);
}

// metaA[c] = {smaxBits, encMinX, encMinY, encMinZ}
// metaB[c] = {0,        encMaxX, encMaxY, encMaxZ}
__global__ __launch_bounds__(256) void hist_kernel(
    const float* __restrict__ sv, int* __restrict__ blkhist,
    unsigned* __restrict__ metaA, unsigned* __restrict__ metaB,
    int N, int nmeta, int nblk)
{
    __shared__ int h[NBUCK];
    const int t = threadIdx.x;
    h[t] = 0;
    __syncthreads();
    int i = blockIdx.x * 256 + t;
    if (i < N) {
        float x = sv[3*i], y = sv[3*i+1], z = sv[3*i+2];
        atomicAdd(&h[bucket_of(x, y, z)], 1);
    }
    __syncthreads();
    blkhist[blockIdx.x * NBUCK + t] = h[t];   // full-row overwrite (poison-safe)
    // box-meta init (separate dispatch from the atomics => race-free):
    // threads 0..31 cover 4 chunks/block, grid covers nmeta with stride
    if (t < 32) {
        int s = t & 7;
        for (int c = blockIdx.x * 4 + (t >> 3); c < nmeta; c += nblk * 4) {
            if (s < 4) metaA[c*4 + s]       = (s == 0) ? 0u : 0xFFFFFFFFu;
            else       metaB[c*4 + (s - 4)] = 0u;
        }
    }
}

__global__ __launch_bounds__(256) void scan_scatter_kernel(
    const float* __restrict__ sv,
    const int*   __restrict__ blkhist,   // [nblk][NBUCK]
    float4*      __restrict__ sorted,    // [N] (x,y,z,bitcast(origIdx))
    unsigned*    __restrict__ metaA,     // [nmeta*4]
    unsigned*    __restrict__ metaB,     // [nmeta*4]
    int N, int ncha, int nblk)
{
    __shared__ int tmp[NBUCK];
    __shared__ int startSh[NBUCK];
    __shared__ int cursor[NBUCK];
    const int t   = threadIdx.x;
    const int blk = blockIdx.x;

    // column sums over block rows (R0-proven: NBUCK=256, unroll 8 pipelines)
    int mine = 0, total = 0;
#pragma unroll 8
    for (int b = 0; b < nblk; ++b) {
        int v = blkhist[b * NBUCK + t];
        if (b < blk) mine += v;
        total += v;
    }
    tmp[t] = total;
    __syncthreads();
    // Kogge-Stone inclusive scan over buckets
    for (int d = 1; d < NBUCK; d <<= 1) {
        int u = (t >= d) ? tmp[t - d] : 0;
        __syncthreads();
        tmp[t] += u;
        __syncthreads();
    }
    int startv = tmp[t] - total;        // exclusive bucket start
    startSh[t] = startv;
    cursor[t]  = startv + mine;         // this block's write base per bucket
    __syncthreads();

    if (blk == 0) {
        // smax per chunk: shell of position c*64 (largest flipped shell s
        // with start[s*8] <= pos); bound = shell upper edge sqrt(NSH-s).
        // Top shell (s==0, may contain |p|^2 >= NSH overflow) -> +inf.
        for (int c = t; c < ncha; c += 256) {
            int pos = c * 64;
            int lo = 0, hi = NSH - 1;
            while (lo < hi) {
                int mid = (lo + hi + 1) >> 1;
                if (startSh[mid << 3] <= pos) lo = mid; else hi = mid - 1;
            }
            float r = (lo == 0) ? 3.0e38f : sqrtf((float)(NSH - lo));
            metaA[c*4] = __float_as_uint(r);
        }
    }

    int i = blk * 256 + t;
    if (i < N) {
        float x = sv[3*i], y = sv[3*i+1], z = sv[3*i+2];
        int b = bucket_of(x, y, z);
        int pos = atomicAdd(&cursor[b], 1);   // LDS atomic
        sorted[pos] = make_float4(x, y, z, __int_as_float(i));
        // exact chunk AABB accumulation (order-independent)
        int c = pos >> 6;
        atomicMin(&metaA[c*4 + 1], encf(x));
        atomicMin(&metaA[c*4 + 2], encf(y));
        atomicMin(&metaA[c*4 + 3], encf(z));
        atomicMax(&metaB[c*4 + 1], encf(x));
        atomicMax(&metaB[c*4 + 2], encf(y));
        atomicMax(&metaB[c*4 + 3], encf(z));
    }
}

template<bool SORTED>
__global__ __launch_bounds__(WAVES * 64) void knn_loss_kernel(
    const float4*   __restrict__ pts,    // sorted points (SORTED only)
    const unsigned* __restrict__ metaA,  // [nmeta*4] smax+boxLo
    const unsigned* __restrict__ metaB,  // [nmeta*4] boxHi
    const float*    __restrict__ sv,     // [N,3]
    const float*    __restrict__ tv,     // [M,3]
    const float*    __restrict__ sn,     // [N,3]
    const float*    __restrict__ tn,     // [M,3]
    float* __restrict__ partial,         // [gridDim.x] per-block sums
    int N, int M, float invM, int ncha)
{
    __shared__ float bsum[WAVES];
    const int lane = threadIdx.x & 63;
    const int w    = threadIdx.x >> 6;
    const int m    = blockIdx.x * WAVES + w;
    const bool valid = (m < M);

    float contrib = 0.0f;
    if (valid) {
        const float tvx = tv[3*m], tvy = tv[3*m+1], tvz = tv[3*m+2];
        const float tlen = sqrtf(tvx*tvx + tvy*tvy + tvz*tvz);

        // ---- bootstrap: bitonic-sort first 64 points desc by (d2, -idx) ----
        float v; int idx;
        {
            int l = (lane < N) ? lane : 0;
            float px, py, pz;
            if (SORTED) {
                float4 q = pts[l];
                px = q.x; py = q.y; pz = q.z; idx = __float_as_int(q.w);
            } else {
                px = sv[3*l]; py = sv[3*l+1]; pz = sv[3*l+2]; idx = l;
            }
            float dx = px - tvx, dy = py - tvy, dz = pz - tvz;
            v = fmaf(dx, dx, fmaf(dy, dy, dz * dz));
            if (lane >= N) { v = -1.0f; idx = 0x7FFFFFFF; }
        }
#pragma unroll
        for (int k = 2; k <= 64; k <<= 1) {
#pragma unroll
            for (int j = k >> 1; j > 0; j >>= 1) {
                float ov = __shfl_xor(v, j);
                int   oi = __shfl_xor(idx, j);
                bool up    = ((lane & k) == 0);   // descending segment
                bool lower = ((lane & j) == 0);
                bool mine  = (v > ov) || (v == ov && idx < oi); // total order
                bool keep  = lower ? (up ? mine : !mine) : (up ? !mine : mine);
                if (!keep) { v = ov; idx = oi; }
            }
        }
        // lanes 0..K-1 now hold the exact top-K of the first 64 (sorted desc)
        float eV = (lane < K) ? v : -1.0f;
        int   eI = idx;
        float thr = __shfl(v, K - 1);   // current 15th-largest d2

        if (SORTED) {
            const uint4* mA4 = (const uint4*)metaA;
            const uint4* mB4 = (const uint4*)metaB;
            uint4 mA = mA4[1], mB = mB4[1];          // prefetched meta
            for (int c = 1; c < ncha; ++c) {
                // radial suffix break (meta already in regs -> no latency)
                float smaxc = __uint_as_float(mA.x);
                float bnd = smaxc + tlen;
                if (bnd * bnd * 1.00001f < thr) break;
                // prefetch next meta (wave-uniform -> scalar loads)
                uint4 mAn = mA4[c + 1], mBn = mB4[c + 1];
                // exact chunk AABB bound on d^2
                float lx = decf(mA.y), ly = decf(mA.z), lz = decf(mA.w);
                float hx = decf(mB.y), hy = decf(mB.z), hz = decf(mB.w);
                float ax = fmaxf((lx-tvx)*(lx-tvx), (hx-tvx)*(hx-tvx));
                float ay = fmaxf((ly-tvy)*(ly-tvy), (hy-tvy)*(hy-tvy));
                float az = fmaxf((lz-tvz)*(lz-tvz), (hz-tvz)*(hz-tvz));
                float bmax2 = ax + ay + az;
                if (bmax2 * 1.00001f >= thr) {       // else: provably no member
                    int  i   = c * 64 + lane;
                    bool has = (i < N);
                    float4 q = pts[has ? i : 0];
                    float dx = q.x - tvx, dy = q.y - tvy, dz = q.z - tvz;
                    float d2 = fmaf(dx, dx, fmaf(dy, dy, dz * dz));
                    int oi2 = __float_as_int(q.w);
                    // >= : equal-d2 candidate with lower idx must displace
                    unsigned long long mb = __ballot(has && (d2 >= thr));
                    while (mb) {
                        int src = __ffsll(mb) - 1;
                        mb &= mb - 1;
                        float cv = __shfl(d2, src);
                        int   ci = __shfl(oi2, src);
                        unsigned long long bb =
                            __ballot((eV > cv) || (eV == cv && eI < ci)) & 0x7FFFull;
                        int p = __popcll(bb);
                        if (p < K) {   // wave-uniform
                            float uv = __shfl_up(eV, 1);
                            int   ui = __shfl_up(eI, 1);
                            if (lane < K) {
                                if (lane == p)      { eV = cv; eI = ci; }
                                else if (lane > p)  { eV = uv; eI = ui; }
                            }
                            thr = __shfl(eV, K - 1);
                            if (mb) mb &= __ballot(d2 >= thr);
                        }
                    }
                }
                mA = mAn; mB = mBn;
            }
        } else {
            for (int ib = 64; ib < N; ib += 64) {
                int  i   = ib + lane;
                bool has = (i < N);
                int g = has ? i : 0;
                float dx = sv[3*g] - tvx, dy = sv[3*g+1] - tvy,
                      dz = sv[3*g+2] - tvz;
                float d2 = fmaf(dx, dx, fmaf(dy, dy, dz * dz));
                int oi2 = i;
                unsigned long long mb = __ballot(has && (d2 >= thr));
                while (mb) {
                    int src = __ffsll(mb) - 1;
                    mb &= mb - 1;
                    float cv = __shfl(d2, src);
                    int   ci = __shfl(oi2, src);
                    unsigned long long bb =
                        __ballot((eV > cv) || (eV == cv && eI < ci)) & 0x7FFFull;
                    int p = __popcll(bb);
                    if (p < K) {
                        float uv = __shfl_up(eV, 1);
                        int   ui = __shfl_up(eI, 1);
                        if (lane < K) {
                            if (lane == p)      { eV = cv; eI = ci; }
                            else if (lane > p)  { eV = uv; eI = ui; }
                        }
                        thr = __shfl(eV, K - 1);
                        if (mb) mb &= __ballot(d2 >= thr);
                    }
                }
            }
        }

        // ---- epilogue: argmin angle, tie-break by top-k rank (= lane) ----
        const float tnx = tn[3*m], tny = tn[3*m+1], tnz = tn[3*m+2];
        float ang = 3.0e38f;
        int myI = eI;
        if (lane < K && myI != 0x7FFFFFFF) {
            float dot = sn[3*myI]*tnx + sn[3*myI+1]*tny + sn[3*myI+2]*tnz;
            dot = fminf(1.0f, fmaxf(-1.0f, dot));
            ang = acosf(dot) * 57.29577951308232f;   // degrees, matches jnp
        }
        float ba = ang; int br = lane; int bi = myI;
#pragma unroll
        for (int s = 1; s < 16; s <<= 1) {
            float oa  = __shfl_xor(ba, s);
            int   orr = __shfl_xor(br, s);
            int   oi  = __shfl_xor(bi, s);
            bool take = (oa < ba) || (oa == ba && orr < br);
            if (take) { ba = oa; br = orr; bi = oi; }
        }
        if (lane == 0) {
            float dx = sv[3*bi]   - tvx;
            float dy = sv[3*bi+1] - tvy;
            float dz = sv[3*bi+2] - tvz;
            contrib = sqrtf(dx*dx + dy*dy + dz*dz) * invM;
        }
    }

    if (lane == 0) bsum[w] = contrib;
    __syncthreads();
    if (threadIdx.x == 0)
        partial[blockIdx.x] = bsum[0] + bsum[1] + bsum[2] + bsum[3];
}

__global__ __launch_bounds__(256) void reduce_kernel(
    const float* __restrict__ partial, float* __restrict__ out, int n)
{
    __shared__ float sh[4];
    const int lane = threadIdx.x & 63;
    const int w    = threadIdx.x >> 6;
    float s = 0.0f;
    for (int i = threadIdx.x; i < n; i += 256) s += partial[i];
#pragma unroll
    for (int d = 1; d < 64; d <<= 1) s += __shfl_xor(s, d);
    if (lane == 0) sh[w] = s;
    __syncthreads();
    if (threadIdx.x == 0) out[0] = sh[0] + sh[1] + sh[2] + sh[3];
}

extern "C" void kernel_launch(void* const* d_in, const int* in_sizes, int n_in,
                              void* d_out, int out_size, void* d_ws, size_t ws_size,
                              hipStream_t stream) {
    const float* sv = (const float*)d_in[0];   // scan_vertices     [1,N,3]
    const float* tv = (const float*)d_in[1];   // template_vertices [1,M,3]
    const float* sn = (const float*)d_in[2];   // scan_normals      [N,3]
    const float* tn = (const float*)d_in[3];   // template_normals  [M,3]
    // d_in[4] = K_knn (fixed 15, compile-time)

    int N = in_sizes[0] / 3;
    int M = in_sizes[1] / 3;
    int ncha  = (N + 63) / 64;                 // 313 chunks
    int nmeta = ncha + 1;                      // +1 prefetch pad
    float* out = (float*)d_out;
    float invM = 1.0f / (float)M;
    int grid  = (M + WAVES - 1) / WAVES;       // 1723
    int nblk  = (N + 255) / 256;               // 79

    // d_ws: [sorted N float4][metaA nmeta*4 u32][metaB nmeta*4 u32]
    //       [blkhist nblk*256 int][partial grid floats]
    size_t offSorted  = 0;
    size_t offMetaA   = offSorted + (size_t)N * sizeof(float4);
    size_t offMetaB   = offMetaA + (size_t)nmeta * 4 * sizeof(unsigned);
    size_t offHist    = offMetaB + (size_t)nmeta * 4 * sizeof(unsigned);
    size_t offPartial = offHist + (size_t)nblk * NBUCK * sizeof(int);
    size_t need       = offPartial + (size_t)grid * sizeof(float);

    if (ws_size >= need) {
        float4*   sorted  = (float4*)  ((char*)d_ws + offSorted);
        unsigned* metaA   = (unsigned*)((char*)d_ws + offMetaA);
        unsigned* metaB   = (unsigned*)((char*)d_ws + offMetaB);
        int*      blkhist = (int*)     ((char*)d_ws + offHist);
        float*    partial = (float*)   ((char*)d_ws + offPartial);

        hist_kernel        <<<nblk, 256, 0, stream>>>(sv, blkhist, metaA,
                                                      metaB, N, nmeta, nblk);
        scan_scatter_kernel<<<nblk, 256, 0, stream>>>(sv, blkhist, sorted,
                                                      metaA, metaB,
                                                      N, ncha, nblk);
        knn_loss_kernel<true><<<grid, WAVES * 64, 0, stream>>>(
            sorted, metaA, metaB, sv, tv, sn, tn, partial, N, M, invM, ncha);
        reduce_kernel      <<<1, 256, 0, stream>>>(partial, out, grid);
    } else if (ws_size >= (size_t)grid * sizeof(float)) {
        float* partial = (float*)d_ws;
        knn_loss_kernel<false><<<grid, WAVES * 64, 0, stream>>>(
            nullptr, nullptr, nullptr, sv, tv, sn, tn, partial, N, M, invM, ncha);
        reduce_kernel<<<1, 256, 0, stream>>>(partial, out, grid);
    }
}